// Round 3
// baseline (667.852 us; speedup 1.0000x reference)
//
#include <hip/hip_runtime.h>

#define N_NODES 100000
#define N_EDGES 3200000
#define D 256
#define CAP 64                      // padded-CSR row capacity (mean deg 32)
#define OVF_MAX 8192

#define BUILD_BLOCKS 3125           // 3.2M edges / (256 thr * 4)
#define CAST_BLOCKS 6250            // 25.6M elems / (256 thr * 16)
#define GEMM_BLOCKS (N_NODES / 16)  // 6250

typedef __attribute__((ext_vector_type(8))) short bf16x8;
typedef __attribute__((ext_vector_type(4))) float f32x4;

// ---------------- static device scratch (rebuilt every call) ----------------
// W^T packed MFMA-fragment-contiguous: [ntile16][kstep8][lane64][8 bf16]
__device__ unsigned short g_wtp[(size_t)16 * 8 * 64 * 8];   // 128 KB
__device__ unsigned short g_xb[(size_t)N_NODES * D];        // 51.2 MB x in bf16
__device__ unsigned       g_y[(size_t)N_NODES * (D / 2)];   // 51.2 MB Y=A*x bf16
__device__ int   g_cursor[N_NODES];                         // per-row degree
__device__ int2  g_pad[(size_t)N_NODES * CAP];              // 51.2 MB {col,val}
__device__ int   g_novf;
__device__ int   g_ovf_row[OVF_MAX];
__device__ int2  g_ovf_edge[OVF_MAX];

// fp32 -> bf16 round-to-nearest-even
__device__ __forceinline__ unsigned short f2bf(float f) {
    unsigned u = __float_as_uint(f);
    unsigned r = u + 0x7fffu + ((u >> 16) & 1u);
    return (unsigned short)(r >> 16);
}

// ---------------------------------- setup: pack W^T bf16 + zero cursors
// packed index p = ((nt*8 + s)*64 + lane)*8 + i :
//   n = nt*16 + (lane&15), k = s*32 + (lane>>4)*8 + i  -> source W[k][n]
__global__ void setup_kernel(const float* __restrict__ W) {
    const int tid = threadIdx.x;
    if (blockIdx.x < 64) {
        int pb = (blockIdx.x * 256 + tid) * 4;
        #pragma unroll
        for (int j = 0; j < 4; ++j) {
            int p    = pb + j;
            int i8   = p & 7;
            int lane = (p >> 3) & 63;
            int s    = (p >> 9) & 7;
            int nt   = p >> 12;
            int n = nt * 16 + (lane & 15);
            int k = s * 32 + (lane >> 4) * 8 + i8;
            g_wtp[p] = f2bf(W[(size_t)k * D + n]);
        }
    }
    for (int i = blockIdx.x * blockDim.x + tid; i < N_NODES;
         i += gridDim.x * blockDim.x)
        g_cursor[i] = 0;
    if (blockIdx.x == 0 && tid == 0) g_novf = 0;
}

// ------- fused: direct padded-CSR build (one global atomic per edge) || cast
// Build: slots within a row are contiguous, so each row's hot region is a few
// L2 lines receiving ~8 records each — sectored dirty-byte tracking keeps the
// HBM write near the logical 26 MB. Cast: x fp32 -> bf16, pure streaming.
__launch_bounds__(256)
__global__ void build_cast_kernel(const float* __restrict__ x,
                                  const float* __restrict__ edge_val,
                                  const int* __restrict__ edge_row,
                                  const int* __restrict__ edge_col) {
    const int tid = threadIdx.x;
    const int b = blockIdx.x;

    if (b < BUILD_BLOCKS) {
        const int e0 = b * 1024;
        #pragma unroll
        for (int j = 0; j < 4; ++j) {
            int e = e0 + j * 256 + tid;          // exact fit: 3125*1024 = N_EDGES
            int r = edge_row[e];
            int c = edge_col[e];
            float v = edge_val[e];
            int slot = atomicAdd(&g_cursor[r], 1);
            int2 pk; pk.x = c; pk.y = __float_as_int(v);
            if (slot < CAP) {
                g_pad[(size_t)r * CAP + slot] = pk;
            } else {
                int o = atomicAdd(&g_novf, 1);
                if (o < OVF_MAX) { g_ovf_row[o] = r; g_ovf_edge[o] = pk; }
            }
        }
    } else {
        // cast: 16 floats per thread, exact-fit grid
        const size_t base = (size_t)(b - BUILD_BLOCKS) * 4096 + (size_t)tid * 16;
        const float4* xp = (const float4*)&x[base];
        float4 f0 = xp[0], f1 = xp[1], f2 = xp[2], f3 = xp[3];
        unsigned short o[16];
        o[ 0]=f2bf(f0.x); o[ 1]=f2bf(f0.y); o[ 2]=f2bf(f0.z); o[ 3]=f2bf(f0.w);
        o[ 4]=f2bf(f1.x); o[ 5]=f2bf(f1.y); o[ 6]=f2bf(f1.z); o[ 7]=f2bf(f1.w);
        o[ 8]=f2bf(f2.x); o[ 9]=f2bf(f2.y); o[10]=f2bf(f2.z); o[11]=f2bf(f2.w);
        o[12]=f2bf(f3.x); o[13]=f2bf(f3.y); o[14]=f2bf(f3.z); o[15]=f2bf(f3.w);
        uint4* dst = (uint4*)&g_xb[base];
        dst[0] = *(const uint4*)&o[0];
        dst[1] = *(const uint4*)&o[8];
    }
}

// ---------------------------------------------------------------- SpMM
// Y = A * x_bf16, bf16 out. One 128-thread block per row (the R0-proven form:
// 85% occupancy, no LDS); thread t owns features 2t, 2t+1.
__launch_bounds__(128)
__global__ void spmm_kernel() {
    const int r = blockIdx.x;
    const int t = threadIdx.x;
    const int deg = g_cursor[r];
    const int dpad = min(deg, CAP);
    const long long* rowp = (const long long*)&g_pad[(size_t)r * CAP];
    const unsigned* xb = (const unsigned*)g_xb;

    float a0 = 0.f, a1 = 0.f;
    int i = 0;
    for (; i + 3 < dpad; i += 4) {
        long long q0 = __builtin_nontemporal_load(&rowp[i]);
        long long q1 = __builtin_nontemporal_load(&rowp[i + 1]);
        long long q2 = __builtin_nontemporal_load(&rowp[i + 2]);
        long long q3 = __builtin_nontemporal_load(&rowp[i + 3]);
        unsigned p0 = xb[(size_t)(int)q0 * (D / 2) + t];
        unsigned p1 = xb[(size_t)(int)q1 * (D / 2) + t];
        unsigned p2 = xb[(size_t)(int)q2 * (D / 2) + t];
        unsigned p3 = xb[(size_t)(int)q3 * (D / 2) + t];
        float v0 = __int_as_float((int)(q0 >> 32));
        float v1 = __int_as_float((int)(q1 >> 32));
        float v2 = __int_as_float((int)(q2 >> 32));
        float v3 = __int_as_float((int)(q3 >> 32));
        a0 += v0 * __uint_as_float(p0 << 16);
        a1 += v0 * __uint_as_float(p0 & 0xffff0000u);
        a0 += v1 * __uint_as_float(p1 << 16);
        a1 += v1 * __uint_as_float(p1 & 0xffff0000u);
        a0 += v2 * __uint_as_float(p2 << 16);
        a1 += v2 * __uint_as_float(p2 & 0xffff0000u);
        a0 += v3 * __uint_as_float(p3 << 16);
        a1 += v3 * __uint_as_float(p3 & 0xffff0000u);
    }
    for (; i < dpad; ++i) {
        long long q0 = __builtin_nontemporal_load(&rowp[i]);
        float v0 = __int_as_float((int)(q0 >> 32));
        unsigned p0 = xb[(size_t)(int)q0 * (D / 2) + t];
        a0 += v0 * __uint_as_float(p0 << 16);
        a1 += v0 * __uint_as_float(p0 & 0xffff0000u);
    }
    const int novf = min(g_novf, OVF_MAX);
    if (novf > 0) {                        // correctness fallback (empty in practice)
        for (int j = 0; j < novf; ++j) {
            if (g_ovf_row[j] == r) {
                int2 e0 = g_ovf_edge[j];
                float v0 = __int_as_float(e0.y);
                unsigned p0 = xb[(size_t)e0.x * (D / 2) + t];
                a0 += v0 * __uint_as_float(p0 << 16);
                a1 += v0 * __uint_as_float(p0 & 0xffff0000u);
            }
        }
    }
    // no relu here: out = relu(Y @ W) happens in the GEMM epilogue
    g_y[(size_t)r * (D / 2) + t] =
        (unsigned)f2bf(a0) | ((unsigned)f2bf(a1) << 16);
}

// --------------------------- out = relu(Y @ W), per-wave 16x64 tile, K=256
__launch_bounds__(256)
__global__ void gemm_kernel(float* __restrict__ out) {
    __shared__ float tile[4][16][68];
    const int g    = blockIdx.x;
    const int wave = threadIdx.x >> 6;
    const int lane = threadIdx.x & 63;
    const int m0   = g * 16;
    const int n0   = wave * 64;
    const int lm   = lane & 15;
    const int q    = lane >> 4;

    const unsigned short* Yb = (const unsigned short*)g_y;
    f32x4 acc0 = {}, acc1 = {}, acc2 = {}, acc3 = {};

    #pragma unroll
    for (int s = 0; s < 8; ++s) {
        bf16x8 av = *(const bf16x8*)&Yb[(size_t)(m0 + lm) * D + s * 32 + q * 8];
        const unsigned short* bp =
            &g_wtp[((size_t)(wave * 4) * 8 + s) * 512 + lane * 8];
        bf16x8 b0 = *(const bf16x8*)&bp[0 * 4096];
        bf16x8 b1 = *(const bf16x8*)&bp[1 * 4096];
        bf16x8 b2 = *(const bf16x8*)&bp[2 * 4096];
        bf16x8 b3 = *(const bf16x8*)&bp[3 * 4096];
        acc0 = __builtin_amdgcn_mfma_f32_16x16x32_bf16(av, b0, acc0, 0, 0, 0);
        acc1 = __builtin_amdgcn_mfma_f32_16x16x32_bf16(av, b1, acc1, 0, 0, 0);
        acc2 = __builtin_amdgcn_mfma_f32_16x16x32_bf16(av, b2, acc2, 0, 0, 0);
        acc3 = __builtin_amdgcn_mfma_f32_16x16x32_bf16(av, b3, acc3, 0, 0, 0);
    }

    #pragma unroll
    for (int r = 0; r < 4; ++r) {
        tile[wave][q * 4 + r][ 0 + lm] = acc0[r];
        tile[wave][q * 4 + r][16 + lm] = acc1[r];
        tile[wave][q * 4 + r][32 + lm] = acc2[r];
        tile[wave][q * 4 + r][48 + lm] = acc3[r];
    }
    const int row  = lane >> 2;
    const int cseg = (lane & 3) * 16;
    float ov[16];
    #pragma unroll
    for (int j = 0; j < 16; ++j)
        ov[j] = fmaxf(tile[wave][row][cseg + j], 0.f);
    float* dst = &out[(size_t)(m0 + row) * D + n0 + cseg];
    #pragma unroll
    for (int j = 0; j < 4; ++j)
        __builtin_nontemporal_store(*(const f32x4*)&ov[j * 4], (f32x4*)&dst[j * 4]);
}

// ---------------------------------------------------------------- launcher
extern "C" void kernel_launch(void* const* d_in, const int* in_sizes, int n_in,
                              void* d_out, int out_size, void* d_ws, size_t ws_size,
                              hipStream_t stream) {
    const float* x        = (const float*)d_in[0];
    const float* weight   = (const float*)d_in[1];
    const float* edge_val = (const float*)d_in[2];
    const int*   edge_row = (const int*)d_in[3];
    const int*   edge_col = (const int*)d_in[4];
    float* out = (float*)d_out;

    setup_kernel<<<64, 256, 0, stream>>>(weight);
    build_cast_kernel<<<BUILD_BLOCKS + CAST_BLOCKS, 256, 0, stream>>>(
        x, edge_val, edge_row, edge_col);
    spmm_kernel<<<N_NODES, 128, 0, stream>>>();
    gemm_kernel<<<GEMM_BLOCKS, 256, 0, stream>>>(out);
}

// Round 4
// 623.620 us; speedup vs baseline: 1.0709x; 1.0709x over previous
//
#include <hip/hip_runtime.h>

#define N_NODES 100000
#define N_EDGES 3200000
#define D 256
#define CAP 64                      // padded-CSR row capacity (mean deg 32)
#define OVF_MAX 8192

#define NB1 98                      // coarse buckets (row >> 10)
#define RPB1 1024                   // rows per coarse bucket
#define CAPB1 34816                 // bucket capacity (mean 32653, +12 sigma)
#define CHUNK 6144                  // edges per binA block (48 KB LDS staging)
#define NBLK_A ((N_EDGES + CHUNK - 1) / CHUNK)   // 521

#define CAST_BLOCKS 6250            // 25.6M elems / (256 thr * 16)
#define GEMM_BLOCKS (N_NODES / 16)  // 6250

typedef __attribute__((ext_vector_type(8))) short bf16x8;
typedef __attribute__((ext_vector_type(4))) float f32x4;

// ---------------- small persistent scratch (always device globals) ----------
__device__ unsigned short g_wtp[(size_t)16 * 8 * 64 * 8];   // 128 KB packed W^T
__device__ int   g_cursor[N_NODES];                         // per-row degree
__device__ int   g_b1cur[NB1];                              // coarse bucket fill
__device__ int   g_novf;
__device__ int   g_ovf_row[OVF_MAX];
__device__ int2  g_ovf_edge[OVF_MAX];

// ---------------- big scratch: d_ws if big enough, else these fallbacks -----
__device__ unsigned short g_xb_fb[(size_t)N_NODES * D];     // 51.2 MB
__device__ unsigned       g_y_fb[(size_t)N_NODES * (D / 2)];// 51.2 MB
__device__ int2           g_pad_fb[(size_t)N_NODES * CAP];  // 51.2 MB
__device__ int2           g_binned_fb[(size_t)NB1 * CAPB1]; // 27.3 MB

// fp32 -> bf16 round-to-nearest-even
__device__ __forceinline__ unsigned short f2bf(float f) {
    unsigned u = __float_as_uint(f);
    unsigned r = u + 0x7fffu + ((u >> 16) & 1u);
    return (unsigned short)(r >> 16);
}

// ---------------------------------- setup: pack W^T bf16 + zero bucket fill
// packed index p = ((nt*8 + s)*64 + lane)*8 + i :
//   n = nt*16 + (lane&15), k = s*32 + (lane>>4)*8 + i  -> source W[k][n]
__global__ void setup_kernel(const float* __restrict__ W) {
    const int tid = threadIdx.x;
    if (blockIdx.x < 64) {
        int pb = (blockIdx.x * 256 + tid) * 4;
        #pragma unroll
        for (int j = 0; j < 4; ++j) {
            int p    = pb + j;
            int i8   = p & 7;
            int lane = (p >> 3) & 63;
            int s    = (p >> 9) & 7;
            int nt   = p >> 12;
            int n = nt * 16 + (lane & 15);
            int k = s * 32 + (lane >> 4) * 8 + i8;
            g_wtp[p] = f2bf(W[(size_t)k * D + n]);
        }
    }
    if (blockIdx.x == 0) {
        if (tid < NB1) g_b1cur[tid] = 0;
        if (tid == 0) g_novf = 0;
    }
}

// ---------------- binA: coarse bin by row>>10 with full-line burst flushes
// Per block: stage CHUNK edges bucket-sorted in LDS, reserve global space with
// one atomic per (block,bucket), flush ~500B contiguous runs. All HBM writes
// are line-sized (the sub-line scatter that cost ~250us in R1-R3 is gone).
__launch_bounds__(256)
__global__ void binA_kernel(const float* __restrict__ edge_val,
                            const int* __restrict__ edge_row,
                            const int* __restrict__ edge_col,
                            int2* __restrict__ binned) {
    __shared__ int2 rec[CHUNK];              // 48 KB
    __shared__ unsigned char bid[CHUNK];     // 6 KB
    __shared__ int cnt[NB1];
    __shared__ int pre[NB1 + 1];
    __shared__ int bas[NB1];
    const int tid = threadIdx.x;
    const int e0 = blockIdx.x * CHUNK;

    for (int k = tid; k < NB1; k += 256) cnt[k] = 0;
    __syncthreads();
    #pragma unroll
    for (int j = 0; j < CHUNK / 256; ++j) {
        int e = e0 + tid + j * 256;
        if (e < N_EDGES) atomicAdd(&cnt[edge_row[e] >> 10], 1);
    }
    __syncthreads();
    if (tid == 0) {                          // serial scan over 98 buckets
        int run = 0;
        for (int k = 0; k < NB1; ++k) { pre[k] = run; run += cnt[k]; }
        pre[NB1] = run;
    }
    __syncthreads();
    for (int k = tid; k < NB1; k += 256)
        bas[k] = cnt[k] ? atomicAdd(&g_b1cur[k], cnt[k]) : 0;
    __syncthreads();
    for (int k = tid; k < NB1; k += 256) cnt[k] = 0;   // reuse as offsets
    __syncthreads();
    #pragma unroll
    for (int j = 0; j < CHUNK / 256; ++j) {
        int e = e0 + tid + j * 256;
        if (e < N_EDGES) {
            int r = edge_row[e];
            int k = r >> 10;
            int o = atomicAdd(&cnt[k], 1);
            int pos = pre[k] + o;
            int2 pk;
            pk.x = edge_col[e] | ((r & 1023) << 17);   // col:17b | row_local:10b
            pk.y = __float_as_int(edge_val[e]);
            rec[pos] = pk;
            bid[pos] = (unsigned char)k;
        }
    }
    __syncthreads();
    const int total = pre[NB1];
    for (int i = tid; i < total; i += 256) {
        int k = bid[i];
        int dest = bas[k] + (i - pre[k]);
        int2 pk = rec[i];
        if (dest < CAPB1) {
            binned[(size_t)k * CAPB1 + dest] = pk;
        } else {
            int o = atomicAdd(&g_novf, 1);
            if (o < OVF_MAX) {
                g_ovf_row[o] = (k << 10) | (pk.x >> 17);
                int2 ov; ov.x = pk.x & 0x1FFFF; ov.y = pk.y;
                g_ovf_edge[o] = ov;
            }
        }
    }
}

// ------- fused: binB (bucket -> padded CSR, L2-local window) || cast x->bf16
// binB block b refines bucket b: scatter destination is a 512 KB window
// (1024 rows x 512 B) that stays L2-resident, so the 8 B scatters coalesce in
// L2 and write back as mostly-dirty lines. Also produces g_cursor (degrees).
__launch_bounds__(256)
__global__ void binB_cast_kernel(const float* __restrict__ x,
                                 const int2* __restrict__ binned,
                                 int2* __restrict__ pad,
                                 unsigned short* __restrict__ xb) {
    __shared__ int cur[RPB1];                // 4 KB
    const int tid = threadIdx.x;
    const int b = blockIdx.x;

    if (b < NB1) {
        for (int i = tid; i < RPB1; i += 256) cur[i] = 0;
        __syncthreads();
        const int n = min(g_b1cur[b], CAPB1);
        const int2* src = &binned[(size_t)b * CAPB1];
        for (int i = tid; i < n; i += 256) {
            int2 pk = src[i];
            int rl  = pk.x >> 17;
            int col = pk.x & 0x1FFFF;
            int slot = atomicAdd(&cur[rl], 1);
            int row = (b << 10) + rl;
            int2 o2; o2.x = col; o2.y = pk.y;
            if (slot < CAP) {
                pad[(size_t)row * CAP + slot] = o2;
            } else {
                int o = atomicAdd(&g_novf, 1);
                if (o < OVF_MAX) { g_ovf_row[o] = row; g_ovf_edge[o] = o2; }
            }
        }
        __syncthreads();
        for (int i = tid; i < RPB1; i += 256) {
            int row = (b << 10) + i;
            if (row < N_NODES) g_cursor[row] = cur[i];
        }
    } else {
        // cast: lane-interleaved float4 loads -> fully coalesced
        const size_t blockBase = (size_t)(b - NB1) * 4096;
        #pragma unroll
        for (int j = 0; j < 4; ++j) {
            size_t idx = blockBase + (size_t)(j * 256 + tid) * 4;
            float4 f = *(const float4*)&x[idx];
            unsigned short o[4];
            o[0] = f2bf(f.x); o[1] = f2bf(f.y);
            o[2] = f2bf(f.z); o[3] = f2bf(f.w);
            *(uint2*)&xb[idx] = *(const uint2*)o;
        }
    }
}

// ---------------------------------------------------------------- SpMM
// Y = A * x_bf16, bf16 out. One 128-thread block per row (R3-proven: 86% occ,
// no LDS); thread t owns features 2t, 2t+1.
__launch_bounds__(128)
__global__ void spmm_kernel(const int2* __restrict__ pad,
                            const unsigned short* __restrict__ xbp,
                            unsigned* __restrict__ y) {
    const int r = blockIdx.x;
    const int t = threadIdx.x;
    const int deg = g_cursor[r];
    const int dpad = min(deg, CAP);
    const long long* rowp = (const long long*)&pad[(size_t)r * CAP];
    const unsigned* xb = (const unsigned*)xbp;

    float a0 = 0.f, a1 = 0.f;
    int i = 0;
    for (; i + 3 < dpad; i += 4) {
        long long q0 = __builtin_nontemporal_load(&rowp[i]);
        long long q1 = __builtin_nontemporal_load(&rowp[i + 1]);
        long long q2 = __builtin_nontemporal_load(&rowp[i + 2]);
        long long q3 = __builtin_nontemporal_load(&rowp[i + 3]);
        unsigned p0 = xb[(size_t)(int)q0 * (D / 2) + t];
        unsigned p1 = xb[(size_t)(int)q1 * (D / 2) + t];
        unsigned p2 = xb[(size_t)(int)q2 * (D / 2) + t];
        unsigned p3 = xb[(size_t)(int)q3 * (D / 2) + t];
        float v0 = __int_as_float((int)(q0 >> 32));
        float v1 = __int_as_float((int)(q1 >> 32));
        float v2 = __int_as_float((int)(q2 >> 32));
        float v3 = __int_as_float((int)(q3 >> 32));
        a0 += v0 * __uint_as_float(p0 << 16);
        a1 += v0 * __uint_as_float(p0 & 0xffff0000u);
        a0 += v1 * __uint_as_float(p1 << 16);
        a1 += v1 * __uint_as_float(p1 & 0xffff0000u);
        a0 += v2 * __uint_as_float(p2 << 16);
        a1 += v2 * __uint_as_float(p2 & 0xffff0000u);
        a0 += v3 * __uint_as_float(p3 << 16);
        a1 += v3 * __uint_as_float(p3 & 0xffff0000u);
    }
    for (; i < dpad; ++i) {
        long long q0 = __builtin_nontemporal_load(&rowp[i]);
        float v0 = __int_as_float((int)(q0 >> 32));
        unsigned p0 = xb[(size_t)(int)q0 * (D / 2) + t];
        a0 += v0 * __uint_as_float(p0 << 16);
        a1 += v0 * __uint_as_float(p0 & 0xffff0000u);
    }
    const int novf = min(g_novf, OVF_MAX);
    if (novf > 0) {                        // correctness fallback (empty in practice)
        for (int j = 0; j < novf; ++j) {
            if (g_ovf_row[j] == r) {
                int2 e0 = g_ovf_edge[j];
                float v0 = __int_as_float(e0.y);
                unsigned p0 = xb[(size_t)e0.x * (D / 2) + t];
                a0 += v0 * __uint_as_float(p0 << 16);
                a1 += v0 * __uint_as_float(p0 & 0xffff0000u);
            }
        }
    }
    // no relu here: out = relu(Y @ W) happens in the GEMM epilogue
    y[(size_t)r * (D / 2) + t] =
        (unsigned)f2bf(a0) | ((unsigned)f2bf(a1) << 16);
}

// --------------------------- out = relu(Y @ W), per-wave 16x64 tile, K=256
__launch_bounds__(256)
__global__ void gemm_kernel(const unsigned short* __restrict__ Yb,
                            float* __restrict__ out) {
    __shared__ float tile[4][16][68];
    const int g    = blockIdx.x;
    const int wave = threadIdx.x >> 6;
    const int lane = threadIdx.x & 63;
    const int m0   = g * 16;
    const int n0   = wave * 64;
    const int lm   = lane & 15;
    const int q    = lane >> 4;

    f32x4 acc0 = {}, acc1 = {}, acc2 = {}, acc3 = {};

    #pragma unroll
    for (int s = 0; s < 8; ++s) {
        bf16x8 av = *(const bf16x8*)&Yb[(size_t)(m0 + lm) * D + s * 32 + q * 8];
        const unsigned short* bp =
            &g_wtp[((size_t)(wave * 4) * 8 + s) * 512 + lane * 8];
        bf16x8 b0 = *(const bf16x8*)&bp[0 * 4096];
        bf16x8 b1 = *(const bf16x8*)&bp[1 * 4096];
        bf16x8 b2 = *(const bf16x8*)&bp[2 * 4096];
        bf16x8 b3 = *(const bf16x8*)&bp[3 * 4096];
        acc0 = __builtin_amdgcn_mfma_f32_16x16x32_bf16(av, b0, acc0, 0, 0, 0);
        acc1 = __builtin_amdgcn_mfma_f32_16x16x32_bf16(av, b1, acc1, 0, 0, 0);
        acc2 = __builtin_amdgcn_mfma_f32_16x16x32_bf16(av, b2, acc2, 0, 0, 0);
        acc3 = __builtin_amdgcn_mfma_f32_16x16x32_bf16(av, b3, acc3, 0, 0, 0);
    }

    #pragma unroll
    for (int r = 0; r < 4; ++r) {
        tile[wave][q * 4 + r][ 0 + lm] = acc0[r];
        tile[wave][q * 4 + r][16 + lm] = acc1[r];
        tile[wave][q * 4 + r][32 + lm] = acc2[r];
        tile[wave][q * 4 + r][48 + lm] = acc3[r];
    }
    const int row  = lane >> 2;
    const int cseg = (lane & 3) * 16;
    float ov[16];
    #pragma unroll
    for (int j = 0; j < 16; ++j)
        ov[j] = fmaxf(tile[wave][row][cseg + j], 0.f);
    float* dst = &out[(size_t)(m0 + row) * D + n0 + cseg];
    #pragma unroll
    for (int j = 0; j < 4; ++j)
        __builtin_nontemporal_store(*(const f32x4*)&ov[j * 4], (f32x4*)&dst[j * 4]);
}

// ---------------------------------------------------------------- launcher
#define XB_BYTES   ((size_t)N_NODES * D * 2)            // 51.2 MB
#define Y_BYTES    ((size_t)N_NODES * D * 2)            // 51.2 MB
#define PAD_BYTES  ((size_t)N_NODES * CAP * 8)          // 51.2 MB
#define BIN_BYTES  ((size_t)NB1 * CAPB1 * 8)            // 27.3 MB
#define ALIGNUP(v) (((v) + 255) & ~(size_t)255)

extern "C" void kernel_launch(void* const* d_in, const int* in_sizes, int n_in,
                              void* d_out, int out_size, void* d_ws, size_t ws_size,
                              hipStream_t stream) {
    const float* x        = (const float*)d_in[0];
    const float* weight   = (const float*)d_in[1];
    const float* edge_val = (const float*)d_in[2];
    const int*   edge_row = (const int*)d_in[3];
    const int*   edge_col = (const int*)d_in[4];
    float* out = (float*)d_out;

    // big scratch: carve from d_ws when possible (avoids any harness
    // save/restore of device globals); fall back to __device__ arrays.
    static void* s_xb = nullptr; static void* s_y = nullptr;
    static void* s_pad = nullptr; static void* s_bin = nullptr;
    if (!s_xb) {
        hipGetSymbolAddress(&s_xb,  HIP_SYMBOL(g_xb_fb));
        hipGetSymbolAddress(&s_y,   HIP_SYMBOL(g_y_fb));
        hipGetSymbolAddress(&s_pad, HIP_SYMBOL(g_pad_fb));
        hipGetSymbolAddress(&s_bin, HIP_SYMBOL(g_binned_fb));
    }
    unsigned short* xb;  unsigned* y;  int2* pad;  int2* binned;
    const size_t need = ALIGNUP(XB_BYTES) + ALIGNUP(Y_BYTES) +
                        ALIGNUP(PAD_BYTES) + ALIGNUP(BIN_BYTES);
    if (d_ws && ws_size >= need) {
        char* p = (char*)d_ws;
        xb     = (unsigned short*)p; p += ALIGNUP(XB_BYTES);
        y      = (unsigned*)p;       p += ALIGNUP(Y_BYTES);
        pad    = (int2*)p;           p += ALIGNUP(PAD_BYTES);
        binned = (int2*)p;
    } else {
        xb     = (unsigned short*)s_xb;
        y      = (unsigned*)s_y;
        pad    = (int2*)s_pad;
        binned = (int2*)s_bin;
    }

    setup_kernel<<<64, 256, 0, stream>>>(weight);
    binA_kernel<<<NBLK_A, 256, 0, stream>>>(edge_val, edge_row, edge_col, binned);
    binB_cast_kernel<<<NB1 + CAST_BLOCKS, 256, 0, stream>>>(x, binned, pad, xb);
    spmm_kernel<<<N_NODES, 128, 0, stream>>>(pad, xb, y);
    gemm_kernel<<<GEMM_BLOCKS, 256, 0, stream>>>((const unsigned short*)y, out);
}